// Round 3
// baseline (204.395 us; speedup 1.0000x reference)
//
#include <hip/hip_runtime.h>
#include <hip/hip_bf16.h>

#define B_DIM 8192
#define D_DIM 256
#define GRID_GEMM 512
#define NT 16   // 32-col tiles per block (512 cols per block)

constexpr float INV_T = 14.285714285714286f;   // 1/0.07; also the logsumexp shift M

typedef __bf16 bf16x8 __attribute__((ext_vector_type(8)));
typedef float  f32x16 __attribute__((ext_vector_type(16)));

#define GLOBAL_U32(p) ((const __attribute__((address_space(1))) unsigned int*)(p))
#define LDS_U32(p)    ((__attribute__((address_space(3))) unsigned int*)(p))

// s_waitcnt imm (gfx9): vm[3:0]=bits3:0, exp=bits6:4, lgkm=bits11:8, vm[5:4]=bits15:14
// vmcnt(8), expcnt/lgkmcnt = no-wait:
#define WAITCNT_VM8 0x0F78

__device__ inline unsigned short f2bf(float f) {
    union { float f; unsigned u; } x; x.f = f;
    unsigned r = x.u + 0x7fffu + ((x.u >> 16) & 1u);  // RNE
    return (unsigned short)(r >> 16);
}

// Fused kernel, PLAIN launch (round-2's hipLaunchCooperativeKernel failed
// silently under the harness's stream/graph machinery -> out stayed 0).
// Co-residency is guaranteed by arithmetic: __launch_bounds__(256,2) caps
// VGPR so 2 blocks/CU always fit (8 waves/CU), LDS 66KB*2=132KB<160KB,
// grid 512 = 2*256 CUs -> all blocks resident before any spins; the
// hand-rolled arrive-and-spin grid barrier cannot deadlock.
// Phase A: q = normalize(h+r), t = normalize(t) -> bf16 ws.
// Phase B: round-0 verified GEMM (4x16KB LDS ring, prefetch dist 2,
// s_waitcnt vmcnt(8), no vmcnt(0) drain) + exp-sum epilogue + lse.
__global__ __launch_bounds__(256, 2) void fused_kernel(
    const float* __restrict__ h, const float* __restrict__ r,
    const float* __restrict__ t,
    unsigned short* __restrict__ qws, unsigned short* __restrict__ tws,
    float* __restrict__ rowsum, float* __restrict__ diagsum,
    int* __restrict__ ticket, int* __restrict__ gbar, float* __restrict__ out)
{
    __shared__ __align__(16) unsigned char ldsB[4][32 * 512];   // 64 KB
    __shared__ float wred[4];
    __shared__ int lastflag;

    const int tid  = threadIdx.x;
    const int lane = tid & 63;
    const int w    = tid >> 6;
    const int l31  = lane & 31;
    const int hi   = lane >> 5;

    // ---------------- phase A: normalization (8 row-tasks per wave) --------
    {
        const int wg = blockIdx.x * 4 + w;        // 0..2047
#pragma unroll
        for (int i = 0; i < 4; ++i) {
            const int row = wg * 4 + i;           // 0..8191
            float4 a4 = ((const float4*)h)[row * 64 + lane];
            float4 b4 = ((const float4*)r)[row * 64 + lane];
            float4 v = make_float4(a4.x + b4.x, a4.y + b4.y,
                                   a4.z + b4.z, a4.w + b4.w);
            float s = v.x * v.x + v.y * v.y + v.z * v.z + v.w * v.w;
#pragma unroll
            for (int off = 32; off; off >>= 1) s += __shfl_xor(s, off, 64);
            float scale = 1.0f / fmaxf(sqrtf(s), 1e-12f);
            ushort4 o;
            o.x = f2bf(v.x * scale); o.y = f2bf(v.y * scale);
            o.z = f2bf(v.z * scale); o.w = f2bf(v.w * scale);
            ((ushort4*)qws)[row * 64 + lane] = o;
        }
#pragma unroll
        for (int i = 0; i < 4; ++i) {
            const int row = wg * 4 + i;
            float4 v = ((const float4*)t)[row * 64 + lane];
            float s = v.x * v.x + v.y * v.y + v.z * v.z + v.w * v.w;
#pragma unroll
            for (int off = 32; off; off >>= 1) s += __shfl_xor(s, off, 64);
            float scale = 1.0f / fmaxf(sqrtf(s), 1e-12f);
            ushort4 o;
            o.x = f2bf(v.x * scale); o.y = f2bf(v.y * scale);
            o.z = f2bf(v.z * scale); o.w = f2bf(v.w * scale);
            ((ushort4*)tws)[row * 64 + lane] = o;
        }
    }

    // ---------------- grid barrier (device scope, arrive-and-spin) ---------
    __threadfence();            // release phase-A stores to agent scope
    __syncthreads();
    if (tid == 0) {
        __hip_atomic_fetch_add(gbar, 1, __ATOMIC_ACQ_REL,
                               __HIP_MEMORY_SCOPE_AGENT);
        while (__hip_atomic_load(gbar, __ATOMIC_ACQUIRE,
                                 __HIP_MEMORY_SCOPE_AGENT) < GRID_GEMM)
            __builtin_amdgcn_s_sleep(1);
    }
    __syncthreads();

    // ---------------- phase B: streaming GEMM + logsumexp ------------------
    const int cc   = blockIdx.x & 15;        // col chunk (fast -> XCD locality)
    const int rb   = blockIdx.x >> 4;        // row block 0..31
    const int row0 = rb * 256 + w * 64;      // this wave's 64 rows
    const int col0 = cc * 512;

    // staging map: slot s -> row n = s>>5, phys chunk p = s&31,
    // logical chunk kc = p ^ (n&7); global ofs = n*512 + kc*16
    int srel[4];
#pragma unroll
    for (int it = 0; it < 4; ++it) {
        int s = it * 256 + tid;
        int n = s >> 5;
        int kc = (s & 31) ^ (n & 7);
        srel[it] = n * 512 + kc * 16;
    }

#define STAGE(snt, bufi)                                                     \
    {                                                                        \
        const unsigned char* gs = (const unsigned char*)tws                  \
                                  + (size_t)(col0 + (snt) * 32) * 512;       \
        _Pragma("unroll")                                                    \
        for (int it = 0; it < 4; ++it)                                       \
            __builtin_amdgcn_global_load_lds(                                \
                GLOBAL_U32(gs + srel[it]),                                   \
                LDS_U32(&ldsB[bufi][(it * 256 + tid) * 16]), 16, 0, 0);      \
    }

    // prologue: tiles 0 and 1 in flight before the A-fragment loads
    STAGE(0, 0);
    STAGE(1, 1);

    // A fragments in registers: rows row0..row0+63, full K=256
    // 32x32x16 A layout: m = lane&31, k = ks*16 + hi*8 + j  (16B per frag)
    bf16x8 a[2][16];
    {
        const unsigned char* abase = (const unsigned char*)qws
                                     + (size_t)(row0 + l31) * 512 + hi * 16;
#pragma unroll
        for (int rt = 0; rt < 2; ++rt)
#pragma unroll
            for (int ks = 0; ks < 16; ++ks)
                a[rt][ks] = *(const bf16x8*)(abase + rt * (32 * 512) + ks * 32);
    }

    f32x16 rowacc[2] = {};
    float diagacc = 0.f;
    const int nsw = l31 & 7;

    for (int nt = 0; nt < NT; ++nt) {
        // prefetch distance 2; tail: dummy re-stage of tile NT-1 into the
        // (dead) target buffer keeps the in-flight count uniform at 8.
        const int snt = (nt + 2 < NT) ? nt + 2 : NT - 1;
        STAGE(snt, (nt + 2) & 3);

        // wait for tile nt's loads only (tiles nt+1, nt+2 = 8 insts stay in
        // flight), then a raw barrier -- NO vmcnt(0) drain.
        __builtin_amdgcn_s_waitcnt(WAITCNT_VM8);
        __builtin_amdgcn_s_barrier();

        const unsigned char* bbuf = ldsB[nt & 3];
        f32x16 acc0 = {}, acc1 = {};
#pragma unroll
        for (int ks = 0; ks < 16; ++ks) {
            int kc = ks * 2 + hi;
            bf16x8 b = *(const bf16x8*)(bbuf + l31 * 512 + ((kc ^ nsw) * 16));
            acc0 = __builtin_amdgcn_mfma_f32_32x32x16_bf16(a[0][ks], b, acc0, 0, 0, 0);
            acc1 = __builtin_amdgcn_mfma_f32_32x32x16_bf16(a[1][ks], b, acc1, 0, 0, 0);
        }

        // hot epilogue: exp-sum only (diag handling hoisted below)
#pragma unroll
        for (int g = 0; g < 16; ++g) {
            rowacc[0][g] += __expf(fmaf(acc0[g], INV_T, -INV_T));
            rowacc[1][g] += __expf(fmaf(acc1[g], INV_T, -INV_T));
        }

        // diagonal tiles: wave-uniform condition, at most 2 of 16 iterations
        const int c0t = col0 + nt * 32;
        if (c0t == row0) {
#pragma unroll
            for (int g = 0; g < 16; ++g) {
                int rm = (g & 3) + 8 * (g >> 2) + 4 * hi;
                if (l31 == rm) diagacc += acc0[g] * INV_T;
            }
        }
        if (c0t == row0 + 32) {
#pragma unroll
            for (int g = 0; g < 16; ++g) {
                int rm = (g & 3) + 8 * (g >> 2) + 4 * hi;
                if (l31 == rm) diagacc += acc1[g] * INV_T;
            }
        }
    }

    // once per block: reduce across the 32 column-lanes, then atomics
#pragma unroll
    for (int rt = 0; rt < 2; ++rt)
#pragma unroll
        for (int g = 0; g < 16; ++g) {
            float s = rowacc[rt][g];
            s += __shfl_xor(s, 1, 64);
            s += __shfl_xor(s, 2, 64);
            s += __shfl_xor(s, 4, 64);
            s += __shfl_xor(s, 8, 64);
            s += __shfl_xor(s, 16, 64);
            if (l31 == 0) {
                int grow = row0 + rt * 32 + (g & 3) + 8 * (g >> 2) + 4 * hi;
                atomicAdd(&rowsum[grow], s);
            }
        }

    float dsum = diagacc;
#pragma unroll
    for (int off = 32; off; off >>= 1) dsum += __shfl_xor(dsum, off, 64);
    if (lane == 0 && dsum != 0.f) atomicAdd(diagsum, dsum);

    // ticket: last block computes the loss
    __syncthreads();
    if (tid == 0) {
        __threadfence();
        int old = __hip_atomic_fetch_add(ticket, 1, __ATOMIC_ACQ_REL,
                                         __HIP_MEMORY_SCOPE_AGENT);
        lastflag = (old == GRID_GEMM - 1);
    }
    __syncthreads();
    if (!lastflag) return;

    float lsum = 0.f;
    for (int rr = tid; rr < B_DIM; rr += 256) {
        float rs = __hip_atomic_load(&rowsum[rr], __ATOMIC_RELAXED,
                                     __HIP_MEMORY_SCOPE_AGENT);
        lsum += __logf(rs);
    }
#pragma unroll
    for (int off = 32; off; off >>= 1) lsum += __shfl_xor(lsum, off, 64);
    if (lane == 0) wred[w] = lsum;
    __syncthreads();
    if (tid == 0) {
        float ds = __hip_atomic_load(diagsum, __ATOMIC_RELAXED,
                                     __HIP_MEMORY_SCOPE_AGENT);
        float total = wred[0] + wred[1] + wred[2] + wred[3]
                    + (float)B_DIM * INV_T   // + M per row
                    - ds;                    // - positive logits
        out[0] = total / (float)B_DIM;
    }
}

extern "C" void kernel_launch(void* const* d_in, const int* in_sizes, int n_in,
                              void* d_out, int out_size, void* d_ws, size_t ws_size,
                              hipStream_t stream)
{
    const float* h = (const float*)d_in[0];
    const float* r = (const float*)d_in[1];
    const float* t = (const float*)d_in[2];

    unsigned char* ws = (unsigned char*)d_ws;
    unsigned short* qws = (unsigned short*)ws;                        // 4 MB
    unsigned short* tws = (unsigned short*)(ws + 4u * 1024 * 1024);   // 4 MB
    float* rowsum  = (float*)(ws + 8u * 1024 * 1024);                 // 32 KB
    float* diagsum = (float*)(ws + 8u * 1024 * 1024 + 32u * 1024);
    int*   ticket  = (int*)  (ws + 8u * 1024 * 1024 + 32u * 1024 + 16);
    int*   gbar    = (int*)  (ws + 8u * 1024 * 1024 + 32u * 1024 + 32);

    // zero rowsum (32 KB) + diagsum/ticket/gbar in one async memset
    hipMemsetAsync(ws + 8u * 1024 * 1024, 0, 32u * 1024 + 64, stream);

    fused_kernel<<<GRID_GEMM, 256, 0, stream>>>(
        h, r, t, qws, tws, rowsum, diagsum, ticket, gbar, (float*)d_out);
}

// Round 4
// 167.022 us; speedup vs baseline: 1.2238x; 1.2238x over previous
//
#include <hip/hip_runtime.h>
#include <hip/hip_bf16.h>

#define B_DIM 8192
#define D_DIM 256
#define GRID_GEMM 512
#define NT 16   // 32-col tiles per block (512 cols per block)

constexpr float INV_T = 14.285714285714286f;   // 1/0.07; also the logsumexp shift M

typedef __bf16 bf16x8 __attribute__((ext_vector_type(8)));
typedef float  f32x16 __attribute__((ext_vector_type(16)));

__device__ inline unsigned short f2bf(float f) {
    union { float f; unsigned u; } x; x.f = f;
    unsigned r = x.u + 0x7fffu + ((x.u >> 16) & 1u);  // RNE
    return (unsigned short)(r >> 16);
}

// Kernel 1: q = normalize(h+r), t = normalize(t) -> bf16 workspace.
// Block 0 additionally zeroes rowsum/diagsum/ticket.
__global__ __launch_bounds__(256) void norm_kernel(
    const float* __restrict__ h, const float* __restrict__ r,
    const float* __restrict__ t,
    unsigned short* __restrict__ qws, unsigned short* __restrict__ tws,
    float* __restrict__ rowsum, float* __restrict__ diagsum, int* __restrict__ ticket)
{
    if (blockIdx.x == 0) {
        float4* rs4 = (float4*)rowsum;
#pragma unroll
        for (int i = 0; i < 8; ++i)
            rs4[threadIdx.x * 8 + i] = make_float4(0.f, 0.f, 0.f, 0.f);
        if (threadIdx.x == 0) { *diagsum = 0.f; *ticket = 0; }
    }

    const int wave = threadIdx.x >> 6;
    const int lane = threadIdx.x & 63;
    const int wid  = blockIdx.x * 4 + wave;      // 0..1023

#pragma unroll
    for (int k = 0; k < 4; ++k) {
        const bool isQ = (k < 2);                 // k=0,1 -> q rows; k=2,3 -> t rows
        const int row = wid * 2 + (k & 1) + (isQ ? 0 : 0);  // two rows per wave per kind
        const int rr  = wid * 2 + (k & 1);
        // rows 0..2047 per wid*2+(k&1)?  grid 1024 * 4 waves * 2 = 8192 rows  ✓
        float4 v;
        if (isQ) {
            float4 a = ((const float4*)h)[(size_t)rr * 64 * 4 / 4 + 0]; // placeholder
            (void)a;
        }
        (void)row;
        break; // (restructured below)
    }

    // --- simple proven mapping: 1024 blocks x 4 waves; each wave does 4 q-rows
    //     then 4 t-rows (8192 rows each kind, 4096 waves x 2 rows... ) ---
    {
        const int wg = blockIdx.x * 4 + wave;     // 0..4095
#pragma unroll
        for (int i = 0; i < 2; ++i) {
            const int row = wg * 2 + i;           // 0..8191
            float4 a = ((const float4*)h)[row * 64 + lane];
            float4 b = ((const float4*)r)[row * 64 + lane];
            float4 v = make_float4(a.x + b.x, a.y + b.y, a.z + b.z, a.w + b.w);
            float s = v.x * v.x + v.y * v.y + v.z * v.z + v.w * v.w;
#pragma unroll
            for (int off = 32; off; off >>= 1) s += __shfl_xor(s, off, 64);
            float scale = 1.0f / fmaxf(sqrtf(s), 1e-12f);
            ushort4 o;
            o.x = f2bf(v.x * scale); o.y = f2bf(v.y * scale);
            o.z = f2bf(v.z * scale); o.w = f2bf(v.w * scale);
            ((ushort4*)qws)[row * 64 + lane] = o;
        }
#pragma unroll
        for (int i = 0; i < 2; ++i) {
            const int row = wg * 2 + i;
            float4 v = ((const float4*)t)[row * 64 + lane];
            float s = v.x * v.x + v.y * v.y + v.z * v.z + v.w * v.w;
#pragma unroll
            for (int off = 32; off; off >>= 1) s += __shfl_xor(s, off, 64);
            float scale = 1.0f / fmaxf(sqrtf(s), 1e-12f);
            ushort4 o;
            o.x = f2bf(v.x * scale); o.y = f2bf(v.y * scale);
            o.z = f2bf(v.z * scale); o.w = f2bf(v.w * scale);
            ((ushort4*)tws)[row * 64 + lane] = o;
        }
    }
}

// Kernel 2: A-in-registers streaming GEMM, NO LDS in the inner loop.
// The B-panel per block is 256 KB and L2-resident (cc = blockIdx&15 keeps
// col chunks XCD-local), so B-fragments are loaded straight from global:
// address tws[(col0+nt*32+l31)*512 + (ks*2+hi)*16] -- byte-identical to what
// the previous STAGE+swizzled-LDS path delivered, so the verified MFMA
// operand mapping is unchanged. No barriers, no vmcnt games, no bank
// conflicts; waves run independent and de-phase (kills the 2-phase convoy
// that held the LDS version at ~10.5k cyc/round vs ~2.5k of pipe work).
__global__ __launch_bounds__(256, 2) void gemm_lse_kernel(
    const unsigned char* __restrict__ qws, const unsigned char* __restrict__ tws,
    float* __restrict__ rowsum, float* __restrict__ diagsum,
    int* __restrict__ ticket, float* __restrict__ out)
{
    __shared__ float wred[4];
    __shared__ int lastflag;

    const int tid  = threadIdx.x;
    const int lane = tid & 63;
    const int w    = tid >> 6;
    const int l31  = lane & 31;
    const int hi   = lane >> 5;

    const int cc   = blockIdx.x & 15;        // col chunk (fast -> XCD locality)
    const int rb   = blockIdx.x >> 4;        // row block 0..31
    const int row0 = rb * 256 + w * 64;      // this wave's 64 rows (distinct per wave)
    const int col0 = cc * 512;

    // ---- A fragments in registers: rows row0..row0+63, full K=256 ----
    // 32x32x16 A layout: m = lane&31, k = ks*16 + hi*8 + j  (16B per frag)
    bf16x8 a[2][16];
    {
        const unsigned char* abase = qws + (size_t)(row0 + l31) * 512 + hi * 16;
#pragma unroll
        for (int rt = 0; rt < 2; ++rt)
#pragma unroll
            for (int ks = 0; ks < 16; ++ks)
                a[rt][ks] = *(const bf16x8*)(abase + rt * (32 * 512) + ks * 32);
    }

    f32x16 rowacc[2] = {};
    float diagacc = 0.f;

    for (int nt = 0; nt < NT; ++nt) {
        // B-fragment base for this tile: lane l31 -> B-col (col0+nt*32+l31),
        // hi selects the 8-element k-half; ks walks K in 32B steps.
        const unsigned char* bb = tws + (size_t)(col0 + nt * 32 + l31) * 512 + hi * 16;

        f32x16 acc0 = {}, acc1 = {};
#pragma unroll
        for (int ks = 0; ks < 16; ++ks) {
            bf16x8 b = *(const bf16x8*)(bb + ks * 32);
            acc0 = __builtin_amdgcn_mfma_f32_32x32x16_bf16(a[0][ks], b, acc0, 0, 0, 0);
            acc1 = __builtin_amdgcn_mfma_f32_32x32x16_bf16(a[1][ks], b, acc1, 0, 0, 0);
        }

        // hot epilogue: exp-sum only (diag handling below, wave-uniform)
#pragma unroll
        for (int g = 0; g < 16; ++g) {
            rowacc[0][g] += __expf(fmaf(acc0[g], INV_T, -INV_T));
            rowacc[1][g] += __expf(fmaf(acc1[g], INV_T, -INV_T));
        }

        // diagonal tiles: wave-uniform condition, at most 2 of 16 iterations
        const int c0t = col0 + nt * 32;
        if (c0t == row0) {
#pragma unroll
            for (int g = 0; g < 16; ++g) {
                int rm = (g & 3) + 8 * (g >> 2) + 4 * hi;
                if (l31 == rm) diagacc += acc0[g] * INV_T;
            }
        }
        if (c0t == row0 + 32) {
#pragma unroll
            for (int g = 0; g < 16; ++g) {
                int rm = (g & 3) + 8 * (g >> 2) + 4 * hi;
                if (l31 == rm) diagacc += acc1[g] * INV_T;
            }
        }
    }

    // ---- once per block: reduce across the 32 column-lanes, then atomics ----
#pragma unroll
    for (int rt = 0; rt < 2; ++rt)
#pragma unroll
        for (int g = 0; g < 16; ++g) {
            float s = rowacc[rt][g];
            s += __shfl_xor(s, 1, 64);
            s += __shfl_xor(s, 2, 64);
            s += __shfl_xor(s, 4, 64);
            s += __shfl_xor(s, 8, 64);
            s += __shfl_xor(s, 16, 64);
            if (l31 == 0) {
                int grow = row0 + rt * 32 + (g & 3) + 8 * (g >> 2) + 4 * hi;
                atomicAdd(&rowsum[grow], s);
            }
        }

    float dsum = diagacc;
#pragma unroll
    for (int off = 32; off; off >>= 1) dsum += __shfl_xor(dsum, off, 64);
    if (lane == 0 && dsum != 0.f) atomicAdd(diagsum, dsum);

    // ---- ticket: last block computes the loss ----
    __syncthreads();
    if (tid == 0) {
        __threadfence();
        int old = __hip_atomic_fetch_add(ticket, 1, __ATOMIC_ACQ_REL,
                                         __HIP_MEMORY_SCOPE_AGENT);
        lastflag = (old == GRID_GEMM - 1);
    }
    __syncthreads();
    if (!lastflag) return;

    float lsum = 0.f;
    for (int rr = tid; rr < B_DIM; rr += 256) {
        float rs = __hip_atomic_load(&rowsum[rr], __ATOMIC_RELAXED,
                                     __HIP_MEMORY_SCOPE_AGENT);
        lsum += __logf(rs);
    }
#pragma unroll
    for (int off = 32; off; off >>= 1) lsum += __shfl_xor(lsum, off, 64);
    if (lane == 0) wred[w] = lsum;
    __syncthreads();
    if (tid == 0) {
        float ds = __hip_atomic_load(diagsum, __ATOMIC_RELAXED,
                                     __HIP_MEMORY_SCOPE_AGENT);
        float total = wred[0] + wred[1] + wred[2] + wred[3]
                    + (float)B_DIM * INV_T   // + M per row
                    - ds;                    // - positive logits
        out[0] = total / (float)B_DIM;
    }
}

extern "C" void kernel_launch(void* const* d_in, const int* in_sizes, int n_in,
                              void* d_out, int out_size, void* d_ws, size_t ws_size,
                              hipStream_t stream)
{
    const float* h = (const float*)d_in[0];
    const float* r = (const float*)d_in[1];
    const float* t = (const float*)d_in[2];

    unsigned char* ws = (unsigned char*)d_ws;
    unsigned short* qws = (unsigned short*)ws;                        // 4 MB
    unsigned short* tws = (unsigned short*)(ws + 4u * 1024 * 1024);   // 4 MB
    float* rowsum  = (float*)(ws + 8u * 1024 * 1024);                 // 32 KB
    float* diagsum = (float*)(ws + 8u * 1024 * 1024 + 32u * 1024);
    int*   ticket  = (int*)  (ws + 8u * 1024 * 1024 + 32u * 1024 + 16);

    norm_kernel<<<1024, 256, 0, stream>>>(h, r, t, qws, tws, rowsum, diagsum, ticket);
    gemm_lse_kernel<<<GRID_GEMM, 256, 0, stream>>>(
        (const unsigned char*)qws, (const unsigned char*)tws,
        rowsum, diagsum, ticket, (float*)d_out);
}

// Round 5
// 146.452 us; speedup vs baseline: 1.3956x; 1.1405x over previous
//
#include <hip/hip_runtime.h>
#include <hip/hip_bf16.h>

#define B_DIM 8192
#define D_DIM 256
#define GRID_GEMM 512
#define NT 16   // 32-col tiles per block (512 cols per block)

constexpr float INV_T = 14.285714285714286f;   // 1/0.07; also the logsumexp shift M

typedef __bf16 bf16x8 __attribute__((ext_vector_type(8)));
typedef float  f32x16 __attribute__((ext_vector_type(16)));

__device__ inline unsigned short f2bf(float f) {
    union { float f; unsigned u; } x; x.f = f;
    unsigned r = x.u + 0x7fffu + ((x.u >> 16) & 1u);  // RNE
    return (unsigned short)(r >> 16);
}

// Kernel 1: q = normalize(h+r) -> row-major bf16; t = normalize(t) -> bf16 in
// MFMA B-FRAGMENT order: byte ((tile*16+ks)*64 + l)*16 holds
// B[col=tile*32+(l&31)][k=ks*16+(l>>5)*8+j], so the GEMM's B-load is one
// fully-coalesced 1KB global load per wave per ks (round 4's 512B-stride
// scatter through L1 was the regression; this moves the layout conversion
// here, once, instead of every round in the hot loop).
// Block 0 additionally zeroes rowsum/diagsum/ticket.
__global__ __launch_bounds__(256) void norm_kernel(
    const float* __restrict__ h, const float* __restrict__ r,
    const float* __restrict__ t,
    unsigned short* __restrict__ qws, unsigned short* __restrict__ tws,
    float* __restrict__ rowsum, float* __restrict__ diagsum, int* __restrict__ ticket)
{
    if (blockIdx.x == 0) {
        float4* rs4 = (float4*)rowsum;
#pragma unroll
        for (int i = 0; i < 8; ++i)
            rs4[threadIdx.x * 8 + i] = make_float4(0.f, 0.f, 0.f, 0.f);
        if (threadIdx.x == 0) { *diagsum = 0.f; *ticket = 0; }
    }

    const int wave = threadIdx.x >> 6;
    const int lane = threadIdx.x & 63;
    const int wg   = blockIdx.x * 4 + wave;      // 0..4095, 2 rows each

    // --- q rows: row-major bf16 (unchanged; A-frags load per-block, cold) ---
#pragma unroll
    for (int i = 0; i < 2; ++i) {
        const int row = wg * 2 + i;              // 0..8191
        float4 a = ((const float4*)h)[row * 64 + lane];
        float4 b = ((const float4*)r)[row * 64 + lane];
        float4 v = make_float4(a.x + b.x, a.y + b.y, a.z + b.z, a.w + b.w);
        float s = v.x * v.x + v.y * v.y + v.z * v.z + v.w * v.w;
#pragma unroll
        for (int off = 32; off; off >>= 1) s += __shfl_xor(s, off, 64);
        float scale = 1.0f / fmaxf(sqrtf(s), 1e-12f);
        ushort4 o;
        o.x = f2bf(v.x * scale); o.y = f2bf(v.y * scale);
        o.z = f2bf(v.z * scale); o.w = f2bf(v.w * scale);
        ((ushort4*)qws)[row * 64 + lane] = o;
    }

    // --- t rows: store in B-fragment order ---
    // lane holds k in [4*lane, 4*lane+4). Fragment coords for chunk kc=k>>3:
    // ks = lane>>2, hi = (lane>>1)&1, sub = lane&1;
    // dst 16B-slot = (tile*16+ks)*64 + hi*32 + (row&31), byte + sub*8.
    {
        const int ks  = lane >> 2;
        const int hi2 = (lane >> 1) & 1;
        const int sub = lane & 1;
#pragma unroll
        for (int i = 0; i < 2; ++i) {
            const int row = wg * 2 + i;
            float4 v = ((const float4*)t)[row * 64 + lane];
            float s = v.x * v.x + v.y * v.y + v.z * v.z + v.w * v.w;
#pragma unroll
            for (int off = 32; off; off >>= 1) s += __shfl_xor(s, off, 64);
            float scale = 1.0f / fmaxf(sqrtf(s), 1e-12f);
            ushort4 o;
            o.x = f2bf(v.x * scale); o.y = f2bf(v.y * scale);
            o.z = f2bf(v.z * scale); o.w = f2bf(v.w * scale);
            size_t slot16 = ((size_t)((row >> 5) * 16 + ks) * 64
                             + (size_t)(hi2 * 32 + (row & 31)));
            *(ushort4*)((unsigned char*)tws + slot16 * 16 + sub * 8) = o;
        }
    }
}

// Kernel 2: A-in-registers streaming GEMM, NO LDS in the inner loop.
// B is pre-transposed into fragment order, so the per-ks B-load is one
// coalesced 1KB global_load_dwordx4 per wave; the 16KB tile is shared by the
// block's 4 waves through L1, the 256KB col-panel through the XCD's L2
// (cc = blockIdx&15 keeps col chunks XCD-local). No barriers, no staging,
// no bank conflicts; waves run independent and de-phase.
__global__ __launch_bounds__(256, 2) void gemm_lse_kernel(
    const unsigned char* __restrict__ qws, const unsigned char* __restrict__ tws,
    float* __restrict__ rowsum, float* __restrict__ diagsum,
    int* __restrict__ ticket, float* __restrict__ out)
{
    __shared__ float wred[4];
    __shared__ int lastflag;

    const int tid  = threadIdx.x;
    const int lane = tid & 63;
    const int w    = tid >> 6;
    const int l31  = lane & 31;
    const int hi   = lane >> 5;

    const int cc   = blockIdx.x & 15;        // col chunk (fast -> XCD locality)
    const int rb   = blockIdx.x >> 4;        // row block 0..31
    const int row0 = rb * 256 + w * 64;      // this wave's 64 rows (distinct per wave)
    const int col0 = cc * 512;
    const int tile0 = cc * 16;               // first 32-col tile of this chunk

    // ---- A fragments in registers: rows row0..row0+63, full K=256 ----
    // 32x32x16 A layout: m = lane&31, k = ks*16 + hi*8 + j  (16B per frag)
    bf16x8 a[2][16];
    {
        const unsigned char* abase = qws + (size_t)(row0 + l31) * 512 + hi * 16;
#pragma unroll
        for (int rt = 0; rt < 2; ++rt)
#pragma unroll
            for (int ks = 0; ks < 16; ++ks)
                a[rt][ks] = *(const bf16x8*)(abase + rt * (32 * 512) + ks * 32);
    }

    f32x16 rowacc[2] = {};
    float diagacc = 0.f;

    for (int nt = 0; nt < NT; ++nt) {
        // B-fragment base: tile (tile0+nt), lane-indexed, coalesced 1KB/inst.
        const unsigned char* bb = tws + (size_t)(tile0 + nt) * 16384 + lane * 16;

        f32x16 acc0 = {}, acc1 = {};
#pragma unroll
        for (int ks = 0; ks < 16; ++ks) {
            bf16x8 b = *(const bf16x8*)(bb + ks * 1024);
            acc0 = __builtin_amdgcn_mfma_f32_32x32x16_bf16(a[0][ks], b, acc0, 0, 0, 0);
            acc1 = __builtin_amdgcn_mfma_f32_32x32x16_bf16(a[1][ks], b, acc1, 0, 0, 0);
        }

        // hot epilogue: exp-sum only (diag handling below, wave-uniform)
#pragma unroll
        for (int g = 0; g < 16; ++g) {
            rowacc[0][g] += __expf(fmaf(acc0[g], INV_T, -INV_T));
            rowacc[1][g] += __expf(fmaf(acc1[g], INV_T, -INV_T));
        }

        // diagonal tiles: wave-uniform condition, at most 2 of 16 iterations
        const int c0t = col0 + nt * 32;
        if (c0t == row0) {
#pragma unroll
            for (int g = 0; g < 16; ++g) {
                int rm = (g & 3) + 8 * (g >> 2) + 4 * hi;
                if (l31 == rm) diagacc += acc0[g] * INV_T;
            }
        }
        if (c0t == row0 + 32) {
#pragma unroll
            for (int g = 0; g < 16; ++g) {
                int rm = (g & 3) + 8 * (g >> 2) + 4 * hi;
                if (l31 == rm) diagacc += acc1[g] * INV_T;
            }
        }
    }

    // ---- once per block: reduce across the 32 column-lanes, then atomics ----
#pragma unroll
    for (int rt = 0; rt < 2; ++rt)
#pragma unroll
        for (int g = 0; g < 16; ++g) {
            float s = rowacc[rt][g];
            s += __shfl_xor(s, 1, 64);
            s += __shfl_xor(s, 2, 64);
            s += __shfl_xor(s, 4, 64);
            s += __shfl_xor(s, 8, 64);
            s += __shfl_xor(s, 16, 64);
            if (l31 == 0) {
                int grow = row0 + rt * 32 + (g & 3) + 8 * (g >> 2) + 4 * hi;
                atomicAdd(&rowsum[grow], s);
            }
        }

    float dsum = diagacc;
#pragma unroll
    for (int off = 32; off; off >>= 1) dsum += __shfl_xor(dsum, off, 64);
    if (lane == 0 && dsum != 0.f) atomicAdd(diagsum, dsum);

    // ---- ticket: last block computes the loss ----
    __syncthreads();
    if (tid == 0) {
        __threadfence();
        int old = __hip_atomic_fetch_add(ticket, 1, __ATOMIC_ACQ_REL,
                                         __HIP_MEMORY_SCOPE_AGENT);
        lastflag = (old == GRID_GEMM - 1);
    }
    __syncthreads();
    if (!lastflag) return;

    float lsum = 0.f;
    for (int rr = tid; rr < B_DIM; rr += 256) {
        float rs = __hip_atomic_load(&rowsum[rr], __ATOMIC_RELAXED,
                                     __HIP_MEMORY_SCOPE_AGENT);
        lsum += __logf(rs);
    }
#pragma unroll
    for (int off = 32; off; off >>= 1) lsum += __shfl_xor(lsum, off, 64);
    if (lane == 0) wred[w] = lsum;
    __syncthreads();
    if (tid == 0) {
        float ds = __hip_atomic_load(diagsum, __ATOMIC_RELAXED,
                                     __HIP_MEMORY_SCOPE_AGENT);
        float total = wred[0] + wred[1] + wred[2] + wred[3]
                    + (float)B_DIM * INV_T   // + M per row
                    - ds;                    // - positive logits
        out[0] = total / (float)B_DIM;
    }
}

extern "C" void kernel_launch(void* const* d_in, const int* in_sizes, int n_in,
                              void* d_out, int out_size, void* d_ws, size_t ws_size,
                              hipStream_t stream)
{
    const float* h = (const float*)d_in[0];
    const float* r = (const float*)d_in[1];
    const float* t = (const float*)d_in[2];

    unsigned char* ws = (unsigned char*)d_ws;
    unsigned short* qws = (unsigned short*)ws;                        // 4 MB
    unsigned short* tws = (unsigned short*)(ws + 4u * 1024 * 1024);   // 4 MB (frag order)
    float* rowsum  = (float*)(ws + 8u * 1024 * 1024);                 // 32 KB
    float* diagsum = (float*)(ws + 8u * 1024 * 1024 + 32u * 1024);
    int*   ticket  = (int*)  (ws + 8u * 1024 * 1024 + 32u * 1024 + 16);

    norm_kernel<<<1024, 256, 0, stream>>>(h, r, t, qws, tws, rowsum, diagsum, ticket);
    gemm_lse_kernel<<<GRID_GEMM, 256, 0, stream>>>(
        (const unsigned char*)qws, (const unsigned char*)tws,
        rowsum, diagsum, ticket, (float*)d_out);
}